// Round 12
// baseline (265.635 us; speedup 1.0000x reference)
//
#include <hip/hip_runtime.h>
#include <math.h>
#include <stdint.h>

#define B_ 8
#define C_ 256
#define HW_ 4096
#define NPIX 32768
#define NELEM (B_*C_*HW_)   // 8388608

typedef __attribute__((ext_vector_type(8))) short short8;
typedef __attribute__((ext_vector_type(4))) float f32x4;

__device__ __forceinline__ unsigned short f2bf(float f) {
    union { float f; uint32_t u; } v; v.f = f;
    uint32_t r = v.u + 0x7FFFu + ((v.u >> 16) & 1u);
    return (unsigned short)(r >> 16);
}
__device__ __forceinline__ float b2f(unsigned short h) {
    union { uint32_t u; float f; } v; v.u = ((uint32_t)h) << 16; return v.f;
}
__device__ __forceinline__ float silu_f(float v) { return v / (1.f + __expf(-v)); }

// unpack 4 bf16 (uint2) -> float4
__device__ __forceinline__ float4 up4(uint2 v) {
    float4 r;
    r.x = b2f((unsigned short)(v.x & 0xffffu));
    r.y = b2f((unsigned short)(v.x >> 16));
    r.z = b2f((unsigned short)(v.y & 0xffffu));
    r.w = b2f((unsigned short)(v.y >> 16));
    return r;
}

// async global->LDS, 16B per lane; LDS dest = wave-uniform base + lane*16.
// Src MUST be lane-contiguous (round-4 lesson: TA request count).
__device__ __forceinline__ void gl2lds16(const void* g, void* l) {
    __builtin_amdgcn_global_load_lds(
        (const __attribute__((address_space(1))) void*)g,
        (__attribute__((address_space(3))) void*)l,
        16, 0, 0);
}

// ---------------- K0: merged weight-prep + x transpose ----------------------
__global__ __launch_bounds__(256) void prep_transpose_kernel(
    const float* __restrict__ akw, const float* __restrict__ l1w,
    const float* __restrict__ cvw, const float* __restrict__ pw,
    unsigned short* __restrict__ wak, unsigned short* __restrict__ wl1,
    unsigned short* __restrict__ wcv, float* __restrict__ pwt,
    const float* __restrict__ x, unsigned short* __restrict__ xt)
{
    __shared__ float tile[64 * 132];
    int blk = blockIdx.x;            // 2376
    int tid = threadIdx.x;
    if (blk < 1024) {
        int b = blk & 7;
        int rest = blk >> 3;             // 0..127
        int half = rest & 1, i = rest >> 1;
        int bi = b * 64 + i;
        {
            int ci_l = tid >> 6, jj = tid & 63;
            const float* ip = x + ((size_t)b * C_ + half * 128 + ci_l) * HW_ + i * 64 + jj;
            #pragma unroll 4
            for (int it = 0; it < 32; ++it)
                tile[jj * 132 + ci_l + it * 4] = ip[(size_t)it * 4 * HW_];
        }
        __syncthreads();
        {
            int j = tid >> 2, q = tid & 3;
            unsigned short* op = xt + ((size_t)(bi * 64 + j)) * 256 + half * 128 + q * 32;
            const float* tp = &tile[j * 132 + q * 32];
            #pragma unroll
            for (int f = 0; f < 4; ++f) {
                union { unsigned short h[8]; uint4 u; } pk;
                #pragma unroll
                for (int e = 0; e < 8; ++e) pk.h[e] = f2bf(tp[f * 8 + e]);
                *(uint4*)(op + f * 8) = pk.u;
            }
        }
        return;
    }
    int gid = (blk - 1024) * 256 + tid;      // 0..346111
    if (gid < 196608) {
        int e = gid & 7;
        int co = (gid >> 3) & 255;
        int q = gid >> 11;            // 0..95
        int kpp = q * 8 + e;          // k'' = n*256+ci
        int n = kpp >> 8, ci = kpp & 255;
        wak[gid] = f2bf(akw[co * 768 + ci * 3 + n]);
    }
    else if (gid < 262144) {
        int g = gid - 196608;
        int e = g & 7, co = (g >> 3) & 255, q = g >> 11;   // q 0..31
        wl1[g] = f2bf(l1w[co * 256 + q * 8 + e]);
    }
    else if (gid < 327680) {
        int g = gid - 262144;
        int e = g & 7, co = (g >> 3) & 255, q = g >> 11;
        wcv[g] = f2bf(cvw[co * 256 + q * 8 + e]);
    }
    else if (gid < 346112) {
        int idx = gid - 327680;
        int ci = idx / 72, r = idx - ci * 72;
        int tt = r / 12, t9 = r - tt * 12;
        pwt[idx] = (t9 < 9) ? pw[tt * 2304 + ci * 9 + t9] : 0.f;
    }
}

// ---------------- K1a: offset conv stage 1 (v5: register acc, small tree) ---
__global__ __launch_bounds__(256) void offset_s1_kernel(
    const float* __restrict__ x, const float* __restrict__ pwt,
    float* __restrict__ part)          // [bi*8+g][6][64]
{
    int blk = blockIdx.x;              // 4096
    int b = blk & 7;
    int rest = blk >> 3;               // 0..511
    int g = rest & 7, i = rest >> 3;
    int bi = b * 64 + i;
    int tid = threadIdx.x;

    __shared__ float tile[6600];       // x tile [(row*66+col)*33+ci]; aliased as s2[16][387]

    // ---- stage x tile (transposed, halo-padded) ----
    {
        int cs = tid >> 3, r8 = tid & 7;
        const float* xp = x + ((size_t)b * C_ + g * 32 + cs) * HW_;
        #pragma unroll
        for (int t = 0; t < 6; ++t) {
            int idx = r8 * 6 + t;
            int r = idx >> 4, v4 = idx & 15;
            int ii = i + r - 1;
            float4 val = make_float4(0.f, 0.f, 0.f, 0.f);
            if (ii >= 0 && ii < 64)
                val = *(const float4*)(xp + ii * 64 + v4 * 4);
            int base = (r * 66 + 1 + v4 * 4) * 33 + cs;
            tile[base]      = val.x;  tile[base + 33]  = val.y;
            tile[base + 66] = val.z;  tile[base + 99]  = val.w;
        }
        if (tid < 192) {
            int ci = tid / 6, rem = tid - ci * 6;
            int ki = rem >> 1, side = rem & 1;
            tile[(ki * 66 + side * 65) * 33 + ci] = 0.f;
        }
    }
    __syncthreads();

    int sub = tid >> 4;                // 0..15
    int jq  = tid & 15;                // 0..15: pixels jq*4 .. jq*4+3

    float acc[6][4];
    #pragma unroll
    for (int tt = 0; tt < 6; ++tt)
        #pragma unroll
        for (int p = 0; p < 4; ++p) acc[tt][p] = 0.f;

    #pragma unroll
    for (int t = 0; t < 2; ++t) {
        int ci = sub + 16 * t;
        float xv[3][6];                // tile cols jq*4 .. jq*4+5
        #pragma unroll
        for (int ki = 0; ki < 3; ++ki)
            #pragma unroll
            for (int cc = 0; cc < 6; ++cc)
                xv[ki][cc] = tile[(ki * 66 + jq * 4 + cc) * 33 + ci];
        const float* wp = pwt + (g * 32 + ci) * 72;
        #pragma unroll
        for (int tt = 0; tt < 6; ++tt) {
            float w[9];
            *(float4*)&w[0] = *(const float4*)(wp + tt * 12);
            *(float4*)&w[4] = *(const float4*)(wp + tt * 12 + 4);
            w[8] = wp[tt * 12 + 8];
            #pragma unroll
            for (int ki = 0; ki < 3; ++ki)
                #pragma unroll
                for (int kj = 0; kj < 3; ++kj) {
                    float wgt = w[ki * 3 + kj];
                    #pragma unroll
                    for (int p = 0; p < 4; ++p)
                        acc[tt][p] += wgt * xv[ki][kj + p];
                }
        }
    }

    // ---- 16-sub reduction via LDS tree (alias tile as s2, stride 387) ----
    __syncthreads();
    {
        float* s2 = tile + sub * 387;
        #pragma unroll
        for (int tt = 0; tt < 6; ++tt)
            #pragma unroll
            for (int p = 0; p < 4; ++p)
                s2[tt * 64 + jq * 4 + p] = acc[tt][p];
    }
    __syncthreads();
    size_t pslot = (size_t)bi * 8 + g;
    for (int idx = tid; idx < 384; idx += 256) {
        float s = 0.f;
        #pragma unroll
        for (int sb = 0; sb < 16; ++sb)
            s += tile[sb * 387 + idx];
        part[pslot * 384 + idx] = s;
    }
}

// ---------------- K2a: gather — inline offset tables + K-tiled writeback ----
__global__ __launch_bounds__(256) void gather_kernel(
    const unsigned short* __restrict__ xt, const float* __restrict__ part,
    const float* __restrict__ pb, unsigned short* __restrict__ v)
{
    int blk = blockIdx.x;          // 1536
    int b = blk & 7;
    int rest = blk >> 3;           // 0..191
    int n = rest >> 6, i = rest & 63;
    int bi = b * 64 + i;           // = pixel-block P
    int tid = threadIdx.x;
    int lane = tid & 63, wv = tid >> 6;
    int ci4 = lane * 4;
    const unsigned short* xb = xt + (size_t)b * 1048576;

    __shared__ unsigned short stile[16640];     // 33.3 KB, padded K-tiled
    __shared__ int2 loff[64];
    __shared__ float4 lw[64];

    // ---- prologue: offset-table for this (b, n, i) ----
    if (tid < 64) {
        int j = tid;
        float vn = pb[n], vn3 = pb[n + 3];
        for (int g = 0; g < 8; ++g) {
            const float* pp = part + ((size_t)bi * 8 + g) * 384;
            vn  += pp[n * 64 + j];
            vn3 += pp[(n + 3) * 64 + j];
        }
        float pnx_n = (n == 2) ? 1.f : 0.f;
        float pny_n = (n == 1) ? 1.f : 0.f;
        float px_ = (float)i + pnx_n + vn;
        float py_ = (float)j + pny_n + vn3;
        float qx = floorf(px_), qy = floorf(py_);
        float qlx = fminf(fmaxf(qx,       0.f), 63.f);
        float qly = fminf(fmaxf(qy,       0.f), 63.f);
        float qrx = fminf(fmaxf(qx + 1.f, 0.f), 63.f);
        float qry = fminf(fmaxf(qy + 1.f, 0.f), 63.f);
        float pxc = fminf(fmaxf(px_,      0.f), 63.f);
        float pyc = fminf(fmaxf(py_,      0.f), 63.f);
        float glt = (1.f + (qlx - pxc)) * (1.f + (qly - pyc));
        float grb = (1.f - (qrx - pxc)) * (1.f - (qry - pyc));
        float glb = (1.f + (qlx - pxc)) * (1.f - (qry - pyc));
        float grt = (1.f - (qrx - pxc)) * (1.f + (qly - pyc));
        int ilx = (int)qlx, irx = (int)qrx;
        int ily = (int)qly, iry = (int)qry;
        int c0; float a0, a1, b0, b1;
        if (ily == iry) {
            if (ily == 0) { c0 = 0;  a0 = glt + glb; a1 = 0.f; b0 = grt + grb; b1 = 0.f; }
            else          { c0 = 62; a0 = 0.f; a1 = glt + glb; b0 = 0.f; b1 = grt + grb; }
        } else { c0 = ily; a0 = glt; a1 = glb; b0 = grt; b1 = grb; }
        loff[j] = make_int2(ilx * 64 + c0, irx * 64 + c0);
        lw[j]   = make_float4(a0, a1, b0, b1);
    }
    __syncthreads();

    int tCloc = ci4 >> 5;                  // 0..7
    int kq = (ci4 >> 3) & 3;
    int e  = ci4 & 7;                      // 0 or 4
    unsigned short* sl = &stile[tCloc * 2080 + kq * 520 + e];

    for (int it0 = 0; it0 < 16; it0 += 8) {
        uint2 A8[8], B8[8], C8[8], D8[8];
        float4 w4[8];
        #pragma unroll
        for (int u = 0; u < 8; ++u) {
            int j = wv * 16 + it0 + u;
            int2 off = loff[j];
            w4[u] = lw[j];
            const unsigned short* p0 = xb + (size_t)off.x * 256 + ci4;
            const unsigned short* p1 = xb + (size_t)off.y * 256 + ci4;
            A8[u] = *(const uint2*)p0;
            B8[u] = *(const uint2*)(p0 + 256);
            C8[u] = *(const uint2*)p1;
            D8[u] = *(const uint2*)(p1 + 256);
        }
        #pragma unroll
        for (int u = 0; u < 8; ++u) {
            int j = wv * 16 + it0 + u;
            float4 A = up4(A8[u]), Bv = up4(B8[u]), Cv = up4(C8[u]), Dv = up4(D8[u]);
            union { unsigned short h[4]; uint2 q; } pk;
            pk.h[0] = f2bf(w4[u].x*A.x + w4[u].y*Bv.x + w4[u].z*Cv.x + w4[u].w*Dv.x);
            pk.h[1] = f2bf(w4[u].x*A.y + w4[u].y*Bv.y + w4[u].z*Cv.y + w4[u].w*Dv.y);
            pk.h[2] = f2bf(w4[u].x*A.z + w4[u].y*Bv.z + w4[u].z*Cv.z + w4[u].w*Dv.z);
            pk.h[3] = f2bf(w4[u].x*A.w + w4[u].y*Bv.w + w4[u].z*Cv.w + w4[u].w*Dv.w);
            *(uint2*)&sl[j * 8] = pk.q;
        }
    }
    __syncthreads();
    // dense writeback: 8 chunks x 4 KB, wave writes 1 KB contiguous/instr
    unsigned short* vb = v + ((size_t)bi * 24 + n * 8) * 2048;
    int kqW = tid >> 6, jW = tid & 63;
    #pragma unroll
    for (int tc = 0; tc < 8; ++tc) {
        *(uint4*)&vb[tc * 2048 + kqW * 512 + jW * 8] =
            *(const uint4*)&stile[tc * 2080 + kqW * 520 + jW * 8];
    }
}

// ---------------- K2b: AK GEMM (bf16 MFMA, co-split 128x64 tiles) -----------
__global__ __launch_bounds__(256) void ak_mfma_kernel(
    const unsigned short* __restrict__ v, const unsigned short* __restrict__ W,
    unsigned short* __restrict__ yh, float* __restrict__ p1, float* __restrict__ p2)
{
    int pid = blockIdx.x;              // 1024
    int mt2 = (pid >> 3) & 1;          // co half; pid and pid+8 share XCD
    int rest = (pid & 7) | ((pid >> 4) << 3);   // pixel block 0..511
    int b = rest & 7, i = rest >> 3;
    int co0 = mt2 * 128;
    int tid = threadIdx.x;
    int wv = tid >> 6, lane = tid & 63;
    int quad = lane >> 4, l15 = lane & 15;
    __shared__ __align__(16) unsigned short sA[4096];   // 8 KB: 4 kq x 128 co x 8
    __shared__ __align__(16) unsigned short sB[2048];   // 4 KB

    const unsigned short* vP = v + (size_t)(b * 64 + i) * 24 * 2048;
    int cS = tid & 127, hS = tid >> 7;      // A-staging decomposition

    f32x4 acc[2][4];
    #pragma unroll
    for (int mt = 0; mt < 2; ++mt)
        #pragma unroll
        for (int nt = 0; nt < 4; ++nt) acc[mt][nt] = (f32x4){0.f, 0.f, 0.f, 0.f};

    for (int t = 0; t < 24; ++t) {
        #pragma unroll
        for (int s = 0; s < 2; ++s) {
            int chunk = hS * 2 + s;         // 0..3 (k-quad)
            gl2lds16(W + ((size_t)(t * 4 + chunk) * 256 + co0 + cS) * 8,
                     &sA[(chunk * 128 + cS) * 8]);
        }
        gl2lds16(vP + (size_t)t * 2048 + tid * 8, &sB[tid * 8]);
        __syncthreads();
        short8 af[2], bf[4];
        #pragma unroll
        for (int mt = 0; mt < 2; ++mt)
            af[mt] = *(const short8*)&sA[(quad * 128 + wv * 32 + mt * 16 + l15) * 8];
        #pragma unroll
        for (int nt = 0; nt < 4; ++nt)
            bf[nt] = *(const short8*)&sB[(quad * 64 + nt * 16 + l15) * 8];
        #pragma unroll
        for (int mt = 0; mt < 2; ++mt)
            #pragma unroll
            for (int nt = 0; nt < 4; ++nt)
                acc[mt][nt] = __builtin_amdgcn_mfma_f32_16x16x32_bf16(
                    af[mt], bf[nt], acc[mt][nt], 0, 0, 0);
        __syncthreads();
    }
    #pragma unroll
    for (int mt = 0; mt < 2; ++mt) {
        #pragma unroll
        for (int r = 0; r < 4; ++r) {
            int co = co0 + wv * 32 + mt * 16 + quad * 4 + r;
            size_t base = ((size_t)b * C_ + co) * HW_ + i * 64;
            float s1 = 0.f, s2 = 0.f;
            #pragma unroll
            for (int nt = 0; nt < 4; ++nt) {
                float val = acc[mt][nt][r];
                s1 += val; s2 += val * val;
                yh[base + nt * 16 + l15] = f2bf(val);
            }
            #pragma unroll
            for (int m = 1; m < 16; m <<= 1) {
                s1 += __shfl_xor(s1, m); s2 += __shfl_xor(s2, m);
            }
            if (l15 == 0) { p1[co * 512 + rest] = s1; p2[co * 512 + rest] = s2; }
        }
    }
}

// ---------------- K4: fused BN-stats + BN+SiLU + 5x5 depthwise --------------
// bn_stats folded into the prologue: each block tree-reduces its channel's
// 512 p1/p2 partials with the SAME reduction order as the old bn_stats
// kernel (bit-identical sc/sh). Block b==0 publishes ss for gemm_fused.
__global__ __launch_bounds__(256) void dw5_fused_kernel(
    const unsigned short* __restrict__ in,
    const float* __restrict__ p1, const float* __restrict__ p2,
    const float* __restrict__ gamma, const float* __restrict__ beta,
    float* __restrict__ ss,
    const float* __restrict__ w, const float* __restrict__ bias,
    unsigned short* __restrict__ out)
{
    int blkI = blockIdx.x;         // 2048
    int b = blkI & 7, c = blkI >> 3;
    int bc = b * 256 + c;
    int tid = threadIdx.x;
    __shared__ float tile[68 * 68];
    __shared__ float r1[256], r2[256];
    __shared__ float scsh[2];

    {   // ---- BN stats (same order as old bn_stats kernel) ----
        float a = p1[c * 512 + tid] + p1[c * 512 + 256 + tid];
        float q = p2[c * 512 + tid] + p2[c * 512 + 256 + tid];
        r1[tid] = a; r2[tid] = q; __syncthreads();
        for (int st = 128; st > 0; st >>= 1) {
            if (tid < st) { r1[tid] += r1[tid + st]; r2[tid] += r2[tid + st]; }
            __syncthreads();
        }
        if (tid == 0) {
            const float inv_n = 1.f / (float)NPIX;
            float m = r1[0] * inv_n;
            float var = r2[0] * inv_n - m * m;
            float sc = gamma[c] * rsqrtf(var + 1e-5f);
            float sh = beta[c] - m * sc;
            scsh[0] = sc; scsh[1] = sh;
            if (b == 0) { ss[c] = sc; ss[256 + c] = sh; }
        }
        __syncthreads();
    }
    float sc = scsh[0], sh = scsh[1];
    const unsigned short* ip = in + (size_t)bc * HW_;
    for (int s = tid; s < 68 * 68; s += 256) {
        int r = s / 68, cc = s - r * 68;
        int ii = r - 2, jj = cc - 2;
        float vv = 0.f;
        if (ii >= 0 && ii < 64 && jj >= 0 && jj < 64) {
            float t = b2f(ip[ii * 64 + jj]) * sc + sh;
            vv = silu_f(t);
        }
        tile[s] = vv;
    }
    float wr[25];
    #pragma unroll
    for (int t = 0; t < 25; ++t) wr[t] = w[c * 25 + t];
    float bv = bias[c];
    __syncthreads();

    int jb = tid & 3, row = tid >> 2;     // 16-col strip, one output row
    int j0 = jb * 16;
    float acc[16];
    #pragma unroll
    for (int j = 0; j < 16; ++j) acc[j] = bv;
    #pragma unroll
    for (int di = 0; di < 5; ++di) {
        const float* tp = &tile[(row + di) * 68 + j0];
        float vv[20];
        #pragma unroll
        for (int q = 0; q < 5; ++q)
            *(float4*)&vv[q * 4] = *(const float4*)(tp + q * 4);
        #pragma unroll
        for (int dj = 0; dj < 5; ++dj) {
            float wv = wr[di * 5 + dj];
            #pragma unroll
            for (int j = 0; j < 16; ++j)
                acc[j] += wv * vv[dj + j];
        }
    }
    unsigned short* op = out + (size_t)bc * HW_ + row * 64 + j0;
    union { unsigned short h[8]; uint4 u; } pk;
    #pragma unroll
    for (int half = 0; half < 2; ++half) {
        #pragma unroll
        for (int j = 0; j < 8; ++j) pk.h[j] = f2bf(acc[half * 8 + j]);
        *(uint4*)&op[half * 8] = pk.u;
    }
}

// ---------------- K5: 7x7 dilated(3) depthwise (16-wide strips) -------------
__global__ __launch_bounds__(256) void dw7d3_kernel(
    const unsigned short* __restrict__ in, const float* __restrict__ w,
    const float* __restrict__ bias, unsigned short* __restrict__ out)
{
    int blkI = blockIdx.x;         // 2048
    int b = blkI & 7, c = blkI >> 3;
    int bc = b * 256 + c;
    int tid = threadIdx.x;
    __shared__ float tile[82 * 84];
    const unsigned short* ip = in + (size_t)bc * HW_;
    for (int s = tid; s < 82 * 84; s += 256) {
        int r = s / 84, cc = s - r * 84;
        int ii = r - 9, jj = cc - 9;
        float vv = 0.f;
        if (ii >= 0 && ii < 64 && jj >= 0 && jj < 64) vv = b2f(ip[ii * 64 + jj]);
        tile[s] = vv;
    }
    float wr[49];
    #pragma unroll
    for (int t = 0; t < 49; ++t) wr[t] = w[c * 49 + t];
    float bv = bias[c];
    __syncthreads();

    int jb = tid & 3, row = tid >> 2;     // 16-col strip, one output row
    int j0 = jb * 16;
    float acc[16];
    #pragma unroll
    for (int j = 0; j < 16; ++j) acc[j] = bv;
    #pragma unroll
    for (int di = 0; di < 7; ++di) {
        const float* tp = &tile[(row + 3 * di) * 84 + j0];
        float vv[36];                 // cols j0 .. j0+35 (<= 83, fits row)
        #pragma unroll
        for (int q = 0; q < 9; ++q)
            *(float4*)&vv[q * 4] = *(const float4*)(tp + q * 4);
        #pragma unroll
        for (int dj = 0; dj < 7; ++dj) {
            float wv = wr[di * 7 + dj];
            #pragma unroll
            for (int j = 0; j < 16; ++j)
                acc[j] += wv * vv[3 * dj + j];
        }
    }
    unsigned short* op = out + (size_t)bc * HW_ + row * 64 + j0;
    union { unsigned short h[8]; uint4 u; } pk;
    #pragma unroll
    for (int half = 0; half < 2; ++half) {
        #pragma unroll
        for (int j = 0; j < 8; ++j) pk.h[j] = f2bf(acc[half * 8 + j]);
        *(uint4*)&op[half * 8] = pk.u;
    }
}

// ---------------- K6: FUSED gemm0(silu-gate) + gemm1(+residual) -------------
// Round-8 geometry (512 blocks x 64px) — measured faster than the 32px
// pixel-split (round-11 regression: W staging is per-block constant, so
// splitting pixels doubles total W-staging work).
__global__ __launch_bounds__(256) void gemm_fused_kernel(
    const unsigned short* __restrict__ in,   // attn (CHW bf16)
    const unsigned short* __restrict__ W0, const float* __restrict__ bias0,
    const unsigned short* __restrict__ W1, const float* __restrict__ bias1,
    const unsigned short* __restrict__ auxh, const float* __restrict__ ss,
    const float* __restrict__ auxf, float* __restrict__ out_f)
{
    int blk = blockIdx.x;              // 512
    int b = blk & 7, i = blk >> 3;
    int tid = threadIdx.x;
    int wv = tid >> 6, lane = tid & 63;
    int quad = lane >> 4, l15 = lane & 15;
    __shared__ __align__(16) unsigned short sA[8192];    // 16 KB
    __shared__ __align__(16) unsigned short sB[2048];    //  4 KB
    __shared__ __align__(16) unsigned short mid[16384];  // 32 KB K-tiled interm.
    int pixS = tid & 63, kqS = tid >> 6;

    const unsigned short* bp = in + ((size_t)b * C_) * HW_ + i * 64 + pixS;

    f32x4 acc[4][4];
    #pragma unroll
    for (int mt = 0; mt < 4; ++mt)
        #pragma unroll
        for (int nt = 0; nt < 4; ++nt) acc[mt][nt] = (f32x4){0.f, 0.f, 0.f, 0.f};

    // ---- phase 1: gemm0 (W0=wl1) ----
    for (int t = 0; t < 8; ++t) {
        #pragma unroll
        for (int s = 0; s < 4; ++s)
            gl2lds16(W0 + ((size_t)(t * 4 + s) * 256 + tid) * 8, &sA[(s * 256 + tid) * 8]);
        {
            const unsigned short* p = bp + (size_t)(t * 32 + kqS * 8) * HW_;
            union { unsigned short h[8]; uint4 u; } hb;
            #pragma unroll
            for (int jj = 0; jj < 8; ++jj) hb.h[jj] = p[(size_t)jj * HW_];
            *(uint4*)&sB[(kqS * 64 + pixS) * 8] = hb.u;
        }
        __syncthreads();
        short8 af[4], bf[4];
        #pragma unroll
        for (int mt = 0; mt < 4; ++mt)
            af[mt] = *(const short8*)&sA[(quad * 256 + wv * 64 + mt * 16 + l15) * 8];
        #pragma unroll
        for (int nt = 0; nt < 4; ++nt)
            bf[nt] = *(const short8*)&sB[(quad * 64 + nt * 16 + l15) * 8];
        #pragma unroll
        for (int mt = 0; mt < 4; ++mt)
            #pragma unroll
            for (int nt = 0; nt < 4; ++nt)
                acc[mt][nt] = __builtin_amdgcn_mfma_f32_16x16x32_bf16(
                    af[mt], bf[nt], acc[mt][nt], 0, 0, 0);
        __syncthreads();
    }
    // epilogue 1: silu-gate, write K-tiled into mid (co becomes gemm1's k)
    #pragma unroll
    for (int mt = 0; mt < 4; ++mt) {
        #pragma unroll
        for (int r = 0; r < 4; ++r) {
            int co = wv * 64 + mt * 16 + quad * 4 + r;
            float bco = bias0[co];
            size_t base = ((size_t)b * C_ + co) * HW_ + i * 64;
            float sc = ss[co], sh = ss[256 + co];
            #pragma unroll
            for (int nt = 0; nt < 4; ++nt) {
                int col = nt * 16 + l15;
                float o = acc[mt][nt][r] + bco;
                float u = silu_f(b2f(auxh[base + col]) * sc + sh);
                mid[((co >> 3) * 64 + col) * 8 + (co & 7)] = f2bf(o * u);
            }
        }
    }
    // ---- phase 2: gemm1 (W1=wcv), B from mid, no staging ----
    #pragma unroll
    for (int mt = 0; mt < 4; ++mt)
        #pragma unroll
        for (int nt = 0; nt < 4; ++nt) acc[mt][nt] = (f32x4){0.f, 0.f, 0.f, 0.f};
    for (int t = 0; t < 8; ++t) {
        #pragma unroll
        for (int s = 0; s < 4; ++s)
            gl2lds16(W1 + ((size_t)(t * 4 + s) * 256 + tid) * 8, &sA[(s * 256 + tid) * 8]);
        __syncthreads();   // also makes mid writes visible at t=0
        short8 af[4], bf[4];
        #pragma unroll
        for (int mt = 0; mt < 4; ++mt)
            af[mt] = *(const short8*)&sA[(quad * 256 + wv * 64 + mt * 16 + l15) * 8];
        #pragma unroll
        for (int nt = 0; nt < 4; ++nt)
            bf[nt] = *(const short8*)&mid[((t * 4 + quad) * 64 + nt * 16 + l15) * 8];
        #pragma unroll
        for (int mt = 0; mt < 4; ++mt)
            #pragma unroll
            for (int nt = 0; nt < 4; ++nt)
                acc[mt][nt] = __builtin_amdgcn_mfma_f32_16x16x32_bf16(
                    af[mt], bf[nt], acc[mt][nt], 0, 0, 0);
        __syncthreads();
    }
    #pragma unroll
    for (int mt = 0; mt < 4; ++mt) {
        #pragma unroll
        for (int r = 0; r < 4; ++r) {
            int co = wv * 64 + mt * 16 + quad * 4 + r;
            float bco = bias1[co];
            size_t base = ((size_t)b * C_ + co) * HW_ + i * 64;
            #pragma unroll
            for (int nt = 0; nt < 4; ++nt) {
                int col = nt * 16 + l15;
                out_f[base + col] = acc[mt][nt][r] + bco + auxf[base + col];
            }
        }
    }
}

// ---------------- launch ----------------------------------------------------
extern "C" void kernel_launch(void* const* d_in, const int* in_sizes, int n_in,
                              void* d_out, int out_size, void* d_ws, size_t ws_size,
                              hipStream_t stream) {
    const float* x     = (const float*)d_in[0];
    const float* p_w   = (const float*)d_in[1];
    const float* p_b   = (const float*)d_in[2];
    const float* ak_w  = (const float*)d_in[3];
    const float* ak_g  = (const float*)d_in[4];
    const float* ak_b  = (const float*)d_in[5];
    const float* l0_w  = (const float*)d_in[6];
    const float* l0_b  = (const float*)d_in[7];
    const float* ls_w  = (const float*)d_in[8];
    const float* ls_b  = (const float*)d_in[9];
    const float* l1_w  = (const float*)d_in[10];
    const float* l1_b  = (const float*)d_in[11];
    const float* cv_w  = (const float*)d_in[12];
    const float* cv_b  = (const float*)d_in[13];
    float* out = (float*)d_out;

    char* w = (char*)d_ws;
    unsigned short* wak = (unsigned short*)(w + 2359296);    // 384 KB
    unsigned short* wl1 = (unsigned short*)(w + 2752512);    // 128 KB
    unsigned short* wcv = (unsigned short*)(w + 2883584);    // 128 KB
    float* p1 = (float*)(w + 3014656);                       // 512 KB
    float* p2 = (float*)(w + 3538944);                       // 512 KB
    float* ss = (float*)(w + 4063232);                       // 2 KB
    float* pwt = (float*)(w + 4065280);                      // 72 KB
    // time-multiplexed regions:
    unsigned short* xt = (unsigned short*)(w + 4194304);     // 16 MB bf16 (dead after gather)
    unsigned short* ybh    = (unsigned short*)(w + 4194304); // 16 MB (ak writes, after gather)
    unsigned short* dw5out = (unsigned short*)(w + 20971520);// 16 MB
    float* part = (float*)(w + 37748736);                    // 6.3 MB (dead after gather)
    unsigned short* attn   = (unsigned short*)(w + 37748736);// 16 MB (dw7 out)
    unsigned short* v      = (unsigned short*)(w + 44040192);// 48 MB (dead after ak)

    prep_transpose_kernel<<<2376, 256, 0, stream>>>(ak_w, l1_w, cv_w, p_w,
                                                    wak, wl1, wcv, pwt, x, xt);
    offset_s1_kernel<<<4096, 256, 0, stream>>>(x, pwt, part);
    gather_kernel<<<1536, 256, 0, stream>>>(xt, part, p_b, v);
    ak_mfma_kernel<<<1024, 256, 0, stream>>>(v, wak, ybh, p1, p2);
    dw5_fused_kernel<<<2048, 256, 0, stream>>>(ybh, p1, p2, ak_g, ak_b, ss,
                                               l0_w, l0_b, dw5out);
    dw7d3_kernel<<<2048, 256, 0, stream>>>(dw5out, ls_w, ls_b, attn);
    gemm_fused_kernel<<<512, 256, 0, stream>>>(attn, wl1, l1_b, wcv, cv_b, ybh, ss, x, out);
}

// Round 13
// 257.000 us; speedup vs baseline: 1.0336x; 1.0336x over previous
//
#include <hip/hip_runtime.h>
#include <math.h>
#include <stdint.h>

#define B_ 8
#define C_ 256
#define HW_ 4096
#define NPIX 32768
#define NELEM (B_*C_*HW_)   // 8388608

typedef __attribute__((ext_vector_type(8))) short short8;
typedef __attribute__((ext_vector_type(4))) float f32x4;

__device__ __forceinline__ unsigned short f2bf(float f) {
    union { float f; uint32_t u; } v; v.f = f;
    uint32_t r = v.u + 0x7FFFu + ((v.u >> 16) & 1u);
    return (unsigned short)(r >> 16);
}
__device__ __forceinline__ float b2f(unsigned short h) {
    union { uint32_t u; float f; } v; v.u = ((uint32_t)h) << 16; return v.f;
}
__device__ __forceinline__ float silu_f(float v) { return v / (1.f + __expf(-v)); }

// unpack 4 bf16 (uint2) -> float4
__device__ __forceinline__ float4 up4(uint2 v) {
    float4 r;
    r.x = b2f((unsigned short)(v.x & 0xffffu));
    r.y = b2f((unsigned short)(v.x >> 16));
    r.z = b2f((unsigned short)(v.y & 0xffffu));
    r.w = b2f((unsigned short)(v.y >> 16));
    return r;
}

// async global->LDS, 16B per lane; LDS dest = wave-uniform base + lane*16.
// Src MUST be lane-contiguous (round-4 lesson: TA request count).
__device__ __forceinline__ void gl2lds16(const void* g, void* l) {
    __builtin_amdgcn_global_load_lds(
        (const __attribute__((address_space(1))) void*)g,
        (__attribute__((address_space(3))) void*)l,
        16, 0, 0);
}

// ---------------- K0: merged weight-prep + x transpose ----------------------
__global__ __launch_bounds__(256) void prep_transpose_kernel(
    const float* __restrict__ akw, const float* __restrict__ l1w,
    const float* __restrict__ cvw, const float* __restrict__ pw,
    unsigned short* __restrict__ wak, unsigned short* __restrict__ wl1,
    unsigned short* __restrict__ wcv, float* __restrict__ pwt,
    const float* __restrict__ x, unsigned short* __restrict__ xt)
{
    __shared__ float tile[64 * 132];
    int blk = blockIdx.x;            // 2376
    int tid = threadIdx.x;
    if (blk < 1024) {
        int b = blk & 7;
        int rest = blk >> 3;             // 0..127
        int half = rest & 1, i = rest >> 1;
        int bi = b * 64 + i;
        {
            int ci_l = tid >> 6, jj = tid & 63;
            const float* ip = x + ((size_t)b * C_ + half * 128 + ci_l) * HW_ + i * 64 + jj;
            #pragma unroll 4
            for (int it = 0; it < 32; ++it)
                tile[jj * 132 + ci_l + it * 4] = ip[(size_t)it * 4 * HW_];
        }
        __syncthreads();
        {
            int j = tid >> 2, q = tid & 3;
            unsigned short* op = xt + ((size_t)(bi * 64 + j)) * 256 + half * 128 + q * 32;
            const float* tp = &tile[j * 132 + q * 32];
            #pragma unroll
            for (int f = 0; f < 4; ++f) {
                union { unsigned short h[8]; uint4 u; } pk;
                #pragma unroll
                for (int e = 0; e < 8; ++e) pk.h[e] = f2bf(tp[f * 8 + e]);
                *(uint4*)(op + f * 8) = pk.u;
            }
        }
        return;
    }
    int gid = (blk - 1024) * 256 + tid;      // 0..346111
    if (gid < 196608) {
        int e = gid & 7;
        int co = (gid >> 3) & 255;
        int q = gid >> 11;            // 0..95
        int kpp = q * 8 + e;          // k'' = n*256+ci
        int n = kpp >> 8, ci = kpp & 255;
        wak[gid] = f2bf(akw[co * 768 + ci * 3 + n]);
    }
    else if (gid < 262144) {
        int g = gid - 196608;
        int e = g & 7, co = (g >> 3) & 255, q = g >> 11;   // q 0..31
        wl1[g] = f2bf(l1w[co * 256 + q * 8 + e]);
    }
    else if (gid < 327680) {
        int g = gid - 262144;
        int e = g & 7, co = (g >> 3) & 255, q = g >> 11;
        wcv[g] = f2bf(cvw[co * 256 + q * 8 + e]);
    }
    else if (gid < 346112) {
        int idx = gid - 327680;
        int ci = idx / 72, r = idx - ci * 72;
        int tt = r / 12, t9 = r - tt * 12;
        pwt[idx] = (t9 < 9) ? pw[tt * 2304 + ci * 9 + t9] : 0.f;
    }
}

// ---------------- K1a: offset conv stage 1 (v5: register acc, small tree) ---
__global__ __launch_bounds__(256) void offset_s1_kernel(
    const float* __restrict__ x, const float* __restrict__ pwt,
    float* __restrict__ part)          // [bi*8+g][6][64]
{
    int blk = blockIdx.x;              // 4096
    int b = blk & 7;
    int rest = blk >> 3;               // 0..511
    int g = rest & 7, i = rest >> 3;
    int bi = b * 64 + i;
    int tid = threadIdx.x;

    __shared__ float tile[6600];       // x tile [(row*66+col)*33+ci]; aliased as s2[16][387]

    // ---- stage x tile (transposed, halo-padded) ----
    {
        int cs = tid >> 3, r8 = tid & 7;
        const float* xp = x + ((size_t)b * C_ + g * 32 + cs) * HW_;
        #pragma unroll
        for (int t = 0; t < 6; ++t) {
            int idx = r8 * 6 + t;
            int r = idx >> 4, v4 = idx & 15;
            int ii = i + r - 1;
            float4 val = make_float4(0.f, 0.f, 0.f, 0.f);
            if (ii >= 0 && ii < 64)
                val = *(const float4*)(xp + ii * 64 + v4 * 4);
            int base = (r * 66 + 1 + v4 * 4) * 33 + cs;
            tile[base]      = val.x;  tile[base + 33]  = val.y;
            tile[base + 66] = val.z;  tile[base + 99]  = val.w;
        }
        if (tid < 192) {
            int ci = tid / 6, rem = tid - ci * 6;
            int ki = rem >> 1, side = rem & 1;
            tile[(ki * 66 + side * 65) * 33 + ci] = 0.f;
        }
    }
    __syncthreads();

    int sub = tid >> 4;                // 0..15
    int jq  = tid & 15;                // 0..15: pixels jq*4 .. jq*4+3

    float acc[6][4];
    #pragma unroll
    for (int tt = 0; tt < 6; ++tt)
        #pragma unroll
        for (int p = 0; p < 4; ++p) acc[tt][p] = 0.f;

    #pragma unroll
    for (int t = 0; t < 2; ++t) {
        int ci = sub + 16 * t;
        float xv[3][6];                // tile cols jq*4 .. jq*4+5
        #pragma unroll
        for (int ki = 0; ki < 3; ++ki)
            #pragma unroll
            for (int cc = 0; cc < 6; ++cc)
                xv[ki][cc] = tile[(ki * 66 + jq * 4 + cc) * 33 + ci];
        const float* wp = pwt + (g * 32 + ci) * 72;
        #pragma unroll
        for (int tt = 0; tt < 6; ++tt) {
            float w[9];
            *(float4*)&w[0] = *(const float4*)(wp + tt * 12);
            *(float4*)&w[4] = *(const float4*)(wp + tt * 12 + 4);
            w[8] = wp[tt * 12 + 8];
            #pragma unroll
            for (int ki = 0; ki < 3; ++ki)
                #pragma unroll
                for (int kj = 0; kj < 3; ++kj) {
                    float wgt = w[ki * 3 + kj];
                    #pragma unroll
                    for (int p = 0; p < 4; ++p)
                        acc[tt][p] += wgt * xv[ki][kj + p];
                }
        }
    }

    // ---- 16-sub reduction via LDS tree (alias tile as s2, stride 387) ----
    __syncthreads();
    {
        float* s2 = tile + sub * 387;
        #pragma unroll
        for (int tt = 0; tt < 6; ++tt)
            #pragma unroll
            for (int p = 0; p < 4; ++p)
                s2[tt * 64 + jq * 4 + p] = acc[tt][p];
    }
    __syncthreads();
    size_t pslot = (size_t)bi * 8 + g;
    for (int idx = tid; idx < 384; idx += 256) {
        float s = 0.f;
        #pragma unroll
        for (int sb = 0; sb < 16; ++sb)
            s += tile[sb * 387 + idx];
        part[pslot * 384 + idx] = s;
    }
}

// ---------------- K2a: gather — inline offset tables + K-tiled writeback ----
__global__ __launch_bounds__(256) void gather_kernel(
    const unsigned short* __restrict__ xt, const float* __restrict__ part,
    const float* __restrict__ pb, unsigned short* __restrict__ v)
{
    int blk = blockIdx.x;          // 1536
    int b = blk & 7;
    int rest = blk >> 3;           // 0..191
    int n = rest >> 6, i = rest & 63;
    int bi = b * 64 + i;           // = pixel-block P
    int tid = threadIdx.x;
    int lane = tid & 63, wv = tid >> 6;
    int ci4 = lane * 4;
    const unsigned short* xb = xt + (size_t)b * 1048576;

    __shared__ unsigned short stile[16640];     // 33.3 KB, padded K-tiled
    __shared__ int2 loff[64];
    __shared__ float4 lw[64];

    // ---- prologue: offset-table for this (b, n, i) ----
    if (tid < 64) {
        int j = tid;
        float vn = pb[n], vn3 = pb[n + 3];
        for (int g = 0; g < 8; ++g) {
            const float* pp = part + ((size_t)bi * 8 + g) * 384;
            vn  += pp[n * 64 + j];
            vn3 += pp[(n + 3) * 64 + j];
        }
        float pnx_n = (n == 2) ? 1.f : 0.f;
        float pny_n = (n == 1) ? 1.f : 0.f;
        float px_ = (float)i + pnx_n + vn;
        float py_ = (float)j + pny_n + vn3;
        float qx = floorf(px_), qy = floorf(py_);
        float qlx = fminf(fmaxf(qx,       0.f), 63.f);
        float qly = fminf(fmaxf(qy,       0.f), 63.f);
        float qrx = fminf(fmaxf(qx + 1.f, 0.f), 63.f);
        float qry = fminf(fmaxf(qy + 1.f, 0.f), 63.f);
        float pxc = fminf(fmaxf(px_,      0.f), 63.f);
        float pyc = fminf(fmaxf(py_,      0.f), 63.f);
        float glt = (1.f + (qlx - pxc)) * (1.f + (qly - pyc));
        float grb = (1.f - (qrx - pxc)) * (1.f - (qry - pyc));
        float glb = (1.f + (qlx - pxc)) * (1.f - (qry - pyc));
        float grt = (1.f - (qrx - pxc)) * (1.f + (qly - pyc));
        int ilx = (int)qlx, irx = (int)qrx;
        int ily = (int)qly, iry = (int)qry;
        int c0; float a0, a1, b0, b1;
        if (ily == iry) {
            if (ily == 0) { c0 = 0;  a0 = glt + glb; a1 = 0.f; b0 = grt + grb; b1 = 0.f; }
            else          { c0 = 62; a0 = 0.f; a1 = glt + glb; b0 = 0.f; b1 = grt + grb; }
        } else { c0 = ily; a0 = glt; a1 = glb; b0 = grt; b1 = grb; }
        loff[j] = make_int2(ilx * 64 + c0, irx * 64 + c0);
        lw[j]   = make_float4(a0, a1, b0, b1);
    }
    __syncthreads();

    int tCloc = ci4 >> 5;                  // 0..7
    int kq = (ci4 >> 3) & 3;
    int e  = ci4 & 7;                      // 0 or 4
    unsigned short* sl = &stile[tCloc * 2080 + kq * 520 + e];

    for (int it0 = 0; it0 < 16; it0 += 8) {
        uint2 A8[8], B8[8], C8[8], D8[8];
        float4 w4[8];
        #pragma unroll
        for (int u = 0; u < 8; ++u) {
            int j = wv * 16 + it0 + u;
            int2 off = loff[j];
            w4[u] = lw[j];
            const unsigned short* p0 = xb + (size_t)off.x * 256 + ci4;
            const unsigned short* p1 = xb + (size_t)off.y * 256 + ci4;
            A8[u] = *(const uint2*)p0;
            B8[u] = *(const uint2*)(p0 + 256);
            C8[u] = *(const uint2*)p1;
            D8[u] = *(const uint2*)(p1 + 256);
        }
        #pragma unroll
        for (int u = 0; u < 8; ++u) {
            int j = wv * 16 + it0 + u;
            float4 A = up4(A8[u]), Bv = up4(B8[u]), Cv = up4(C8[u]), Dv = up4(D8[u]);
            union { unsigned short h[4]; uint2 q; } pk;
            pk.h[0] = f2bf(w4[u].x*A.x + w4[u].y*Bv.x + w4[u].z*Cv.x + w4[u].w*Dv.x);
            pk.h[1] = f2bf(w4[u].x*A.y + w4[u].y*Bv.y + w4[u].z*Cv.y + w4[u].w*Dv.y);
            pk.h[2] = f2bf(w4[u].x*A.z + w4[u].y*Bv.z + w4[u].z*Cv.z + w4[u].w*Dv.z);
            pk.h[3] = f2bf(w4[u].x*A.w + w4[u].y*Bv.w + w4[u].z*Cv.w + w4[u].w*Dv.w);
            *(uint2*)&sl[j * 8] = pk.q;
        }
    }
    __syncthreads();
    // dense writeback: 8 chunks x 4 KB, wave writes 1 KB contiguous/instr
    unsigned short* vb = v + ((size_t)bi * 24 + n * 8) * 2048;
    int kqW = tid >> 6, jW = tid & 63;
    #pragma unroll
    for (int tc = 0; tc < 8; ++tc) {
        *(uint4*)&vb[tc * 2048 + kqW * 512 + jW * 8] =
            *(const uint4*)&stile[tc * 2080 + kqW * 520 + jW * 8];
    }
}

// ---------------- K2b: AK GEMM (bf16 MFMA, co-split 128x64 tiles) -----------
__global__ __launch_bounds__(256) void ak_mfma_kernel(
    const unsigned short* __restrict__ v, const unsigned short* __restrict__ W,
    unsigned short* __restrict__ yh, float* __restrict__ p1, float* __restrict__ p2)
{
    int pid = blockIdx.x;              // 1024
    int mt2 = (pid >> 3) & 1;          // co half; pid and pid+8 share XCD
    int rest = (pid & 7) | ((pid >> 4) << 3);   // pixel block 0..511
    int b = rest & 7, i = rest >> 3;
    int co0 = mt2 * 128;
    int tid = threadIdx.x;
    int wv = tid >> 6, lane = tid & 63;
    int quad = lane >> 4, l15 = lane & 15;
    __shared__ __align__(16) unsigned short sA[4096];   // 8 KB: 4 kq x 128 co x 8
    __shared__ __align__(16) unsigned short sB[2048];   // 4 KB

    const unsigned short* vP = v + (size_t)(b * 64 + i) * 24 * 2048;
    int cS = tid & 127, hS = tid >> 7;      // A-staging decomposition

    f32x4 acc[2][4];
    #pragma unroll
    for (int mt = 0; mt < 2; ++mt)
        #pragma unroll
        for (int nt = 0; nt < 4; ++nt) acc[mt][nt] = (f32x4){0.f, 0.f, 0.f, 0.f};

    for (int t = 0; t < 24; ++t) {
        #pragma unroll
        for (int s = 0; s < 2; ++s) {
            int chunk = hS * 2 + s;         // 0..3 (k-quad)
            gl2lds16(W + ((size_t)(t * 4 + chunk) * 256 + co0 + cS) * 8,
                     &sA[(chunk * 128 + cS) * 8]);
        }
        gl2lds16(vP + (size_t)t * 2048 + tid * 8, &sB[tid * 8]);
        __syncthreads();
        short8 af[2], bf[4];
        #pragma unroll
        for (int mt = 0; mt < 2; ++mt)
            af[mt] = *(const short8*)&sA[(quad * 128 + wv * 32 + mt * 16 + l15) * 8];
        #pragma unroll
        for (int nt = 0; nt < 4; ++nt)
            bf[nt] = *(const short8*)&sB[(quad * 64 + nt * 16 + l15) * 8];
        #pragma unroll
        for (int mt = 0; mt < 2; ++mt)
            #pragma unroll
            for (int nt = 0; nt < 4; ++nt)
                acc[mt][nt] = __builtin_amdgcn_mfma_f32_16x16x32_bf16(
                    af[mt], bf[nt], acc[mt][nt], 0, 0, 0);
        __syncthreads();
    }
    #pragma unroll
    for (int mt = 0; mt < 2; ++mt) {
        #pragma unroll
        for (int r = 0; r < 4; ++r) {
            int co = co0 + wv * 32 + mt * 16 + quad * 4 + r;
            size_t base = ((size_t)b * C_ + co) * HW_ + i * 64;
            float s1 = 0.f, s2 = 0.f;
            #pragma unroll
            for (int nt = 0; nt < 4; ++nt) {
                float val = acc[mt][nt][r];
                s1 += val; s2 += val * val;
                yh[base + nt * 16 + l15] = f2bf(val);
            }
            #pragma unroll
            for (int m = 1; m < 16; m <<= 1) {
                s1 += __shfl_xor(s1, m); s2 += __shfl_xor(s2, m);
            }
            if (l15 == 0) { p1[co * 512 + rest] = s1; p2[co * 512 + rest] = s2; }
        }
    }
}

// ---------------- K3: BN stats from partials --------------------------------
__global__ __launch_bounds__(256) void bn_stats_kernel(
    const float* __restrict__ p1, const float* __restrict__ p2,
    const float* __restrict__ gamma, const float* __restrict__ beta,
    float* __restrict__ ss)
{
    int co = blockIdx.x, tid = threadIdx.x;     // grid=256
    float a = p1[co * 512 + tid] + p1[co * 512 + 256 + tid];
    float q = p2[co * 512 + tid] + p2[co * 512 + 256 + tid];
    __shared__ float r1[256], r2[256];
    r1[tid] = a; r2[tid] = q; __syncthreads();
    for (int st = 128; st > 0; st >>= 1) {
        if (tid < st) { r1[tid] += r1[tid + st]; r2[tid] += r2[tid + st]; }
        __syncthreads();
    }
    if (tid == 0) {
        const float inv_n = 1.f / (float)NPIX;
        float m = r1[0] * inv_n;
        float var = r2[0] * inv_n - m * m;
        float sc = gamma[co] * rsqrtf(var + 1e-5f);
        ss[co] = sc; ss[256 + co] = beta[co] - m * sc;
    }
}

// ---------------- K4: fused BN+SiLU + 5x5 depthwise (16-wide strips) --------
__global__ __launch_bounds__(256) void dw5_fused_kernel(
    const unsigned short* __restrict__ in, const float* __restrict__ ss,
    const float* __restrict__ w, const float* __restrict__ bias,
    unsigned short* __restrict__ out)
{
    int blkI = blockIdx.x;         // 2048
    int b = blkI & 7, c = blkI >> 3;
    int bc = b * 256 + c;
    int tid = threadIdx.x;
    __shared__ float tile[68 * 68];
    float sc = ss[c], sh = ss[256 + c];
    const unsigned short* ip = in + (size_t)bc * HW_;
    for (int s = tid; s < 68 * 68; s += 256) {
        int r = s / 68, cc = s - r * 68;
        int ii = r - 2, jj = cc - 2;
        float vv = 0.f;
        if (ii >= 0 && ii < 64 && jj >= 0 && jj < 64) {
            float t = b2f(ip[ii * 64 + jj]) * sc + sh;
            vv = silu_f(t);
        }
        tile[s] = vv;
    }
    float wr[25];
    #pragma unroll
    for (int t = 0; t < 25; ++t) wr[t] = w[c * 25 + t];
    float bv = bias[c];
    __syncthreads();

    int jb = tid & 3, row = tid >> 2;     // 16-col strip, one output row
    int j0 = jb * 16;
    float acc[16];
    #pragma unroll
    for (int j = 0; j < 16; ++j) acc[j] = bv;
    #pragma unroll
    for (int di = 0; di < 5; ++di) {
        const float* tp = &tile[(row + di) * 68 + j0];
        float vv[20];
        #pragma unroll
        for (int q = 0; q < 5; ++q)
            *(float4*)&vv[q * 4] = *(const float4*)(tp + q * 4);
        #pragma unroll
        for (int dj = 0; dj < 5; ++dj) {
            float wv = wr[di * 5 + dj];
            #pragma unroll
            for (int j = 0; j < 16; ++j)
                acc[j] += wv * vv[dj + j];
        }
    }
    unsigned short* op = out + (size_t)bc * HW_ + row * 64 + j0;
    union { unsigned short h[8]; uint4 u; } pk;
    #pragma unroll
    for (int half = 0; half < 2; ++half) {
        #pragma unroll
        for (int j = 0; j < 8; ++j) pk.h[j] = f2bf(acc[half * 8 + j]);
        *(uint4*)&op[half * 8] = pk.u;
    }
}

// ---------------- K5: 7x7 dilated(3) depthwise (16-wide strips) -------------
__global__ __launch_bounds__(256) void dw7d3_kernel(
    const unsigned short* __restrict__ in, const float* __restrict__ w,
    const float* __restrict__ bias, unsigned short* __restrict__ out)
{
    int blkI = blockIdx.x;         // 2048
    int b = blkI & 7, c = blkI >> 3;
    int bc = b * 256 + c;
    int tid = threadIdx.x;
    __shared__ float tile[82 * 84];
    const unsigned short* ip = in + (size_t)bc * HW_;
    for (int s = tid; s < 82 * 84; s += 256) {
        int r = s / 84, cc = s - r * 84;
        int ii = r - 9, jj = cc - 9;
        float vv = 0.f;
        if (ii >= 0 && ii < 64 && jj >= 0 && jj < 64) vv = b2f(ip[ii * 64 + jj]);
        tile[s] = vv;
    }
    float wr[49];
    #pragma unroll
    for (int t = 0; t < 49; ++t) wr[t] = w[c * 49 + t];
    float bv = bias[c];
    __syncthreads();

    int jb = tid & 3, row = tid >> 2;     // 16-col strip, one output row
    int j0 = jb * 16;
    float acc[16];
    #pragma unroll
    for (int j = 0; j < 16; ++j) acc[j] = bv;
    #pragma unroll
    for (int di = 0; di < 7; ++di) {
        const float* tp = &tile[(row + 3 * di) * 84 + j0];
        float vv[36];                 // cols j0 .. j0+35 (<= 83, fits row)
        #pragma unroll
        for (int q = 0; q < 9; ++q)
            *(float4*)&vv[q * 4] = *(const float4*)(tp + q * 4);
        #pragma unroll
        for (int dj = 0; dj < 7; ++dj) {
            float wv = wr[di * 7 + dj];
            #pragma unroll
            for (int j = 0; j < 16; ++j)
                acc[j] += wv * vv[3 * dj + j];
        }
    }
    unsigned short* op = out + (size_t)bc * HW_ + row * 64 + j0;
    union { unsigned short h[8]; uint4 u; } pk;
    #pragma unroll
    for (int half = 0; half < 2; ++half) {
        #pragma unroll
        for (int j = 0; j < 8; ++j) pk.h[j] = f2bf(acc[half * 8 + j]);
        *(uint4*)&op[half * 8] = pk.u;
    }
}

// ---------------- K6: FUSED gemm0+gemm1, 32-pixel tiles (4 blocks/CU) -------
__global__ __launch_bounds__(256) void gemm_fused_kernel(
    const unsigned short* __restrict__ in,   // attn (CHW bf16)
    const unsigned short* __restrict__ W0, const float* __restrict__ bias0,
    const unsigned short* __restrict__ W1, const float* __restrict__ bias1,
    const unsigned short* __restrict__ auxh, const float* __restrict__ ss,
    const float* __restrict__ auxf, float* __restrict__ out_f)
{
    int blk = blockIdx.x;              // 1024
    int b = blk & 7;
    int rest = blk >> 3;               // 0..127
    int half = rest & 1, i = rest >> 1;
    int pix0 = i * 64 + half * 32;
    int tid = threadIdx.x;
    int wv = tid >> 6, lane = tid & 63;
    int quad = lane >> 4, l15 = lane & 15;
    __shared__ __align__(16) unsigned short sA[8192];   // 16 KB (256co x 32k)
    __shared__ __align__(16) unsigned short sB[1024];   //  2 KB (4kq x 32px x 8)
    __shared__ __align__(16) unsigned short mid[8192];  // 16 KB (32kg x 32px x 8)
    int pxS = tid & 31, kqS = (tid >> 5) & 3;           // B-staging (threads 0..127)

    const unsigned short* bp = in + ((size_t)b * C_) * HW_ + pix0 + pxS;

    f32x4 acc[4][2];
    #pragma unroll
    for (int mt = 0; mt < 4; ++mt)
        #pragma unroll
        for (int nt = 0; nt < 2; ++nt) acc[mt][nt] = (f32x4){0.f, 0.f, 0.f, 0.f};

    // ---- phase 1: gemm0 (W0=wl1) ----
    for (int t = 0; t < 8; ++t) {
        #pragma unroll
        for (int s = 0; s < 4; ++s)
            gl2lds16(W0 + ((size_t)(t * 4 + s) * 256 + tid) * 8, &sA[(s * 256 + tid) * 8]);
        if (tid < 128) {
            const unsigned short* p = bp + (size_t)(t * 32 + kqS * 8) * HW_;
            union { unsigned short h[8]; uint4 u; } hb;
            #pragma unroll
            for (int jj = 0; jj < 8; ++jj) hb.h[jj] = p[(size_t)jj * HW_];
            *(uint4*)&sB[(kqS * 32 + pxS) * 8] = hb.u;
        }
        __syncthreads();
        short8 af[4], bf[2];
        #pragma unroll
        for (int mt = 0; mt < 4; ++mt)
            af[mt] = *(const short8*)&sA[(quad * 256 + wv * 64 + mt * 16 + l15) * 8];
        #pragma unroll
        for (int nt = 0; nt < 2; ++nt)
            bf[nt] = *(const short8*)&sB[(quad * 32 + nt * 16 + l15) * 8];
        #pragma unroll
        for (int mt = 0; mt < 4; ++mt)
            #pragma unroll
            for (int nt = 0; nt < 2; ++nt)
                acc[mt][nt] = __builtin_amdgcn_mfma_f32_16x16x32_bf16(
                    af[mt], bf[nt], acc[mt][nt], 0, 0, 0);
        __syncthreads();
    }
    // epilogue 1: silu-gate, write K-tiled into mid (co becomes gemm1's k)
    #pragma unroll
    for (int mt = 0; mt < 4; ++mt) {
        #pragma unroll
        for (int r = 0; r < 4; ++r) {
            int co = wv * 64 + mt * 16 + quad * 4 + r;
            float bco = bias0[co];
            size_t base = ((size_t)b * C_ + co) * HW_ + pix0;
            float sc = ss[co], sh = ss[256 + co];
            #pragma unroll
            for (int nt = 0; nt < 2; ++nt) {
                int col = nt * 16 + l15;
                float o = acc[mt][nt][r] + bco;
                float u = silu_f(b2f(auxh[base + col]) * sc + sh);
                mid[((co >> 3) * 32 + col) * 8 + (co & 7)] = f2bf(o * u);
            }
        }
    }
    // ---- phase 2: gemm1 (W1=wcv), B from mid, no staging ----
    #pragma unroll
    for (int mt = 0; mt < 4; ++mt)
        #pragma unroll
        for (int nt = 0; nt < 2; ++nt) acc[mt][nt] = (f32x4){0.f, 0.f, 0.f, 0.f};
    for (int t = 0; t < 8; ++t) {
        #pragma unroll
        for (int s = 0; s < 4; ++s)
            gl2lds16(W1 + ((size_t)(t * 4 + s) * 256 + tid) * 8, &sA[(s * 256 + tid) * 8]);
        __syncthreads();   // also makes mid writes visible at t=0
        short8 af[4], bf[2];
        #pragma unroll
        for (int mt = 0; mt < 4; ++mt)
            af[mt] = *(const short8*)&sA[(quad * 256 + wv * 64 + mt * 16 + l15) * 8];
        #pragma unroll
        for (int nt = 0; nt < 2; ++nt)
            bf[nt] = *(const short8*)&mid[((t * 4 + quad) * 32 + nt * 16 + l15) * 8];
        #pragma unroll
        for (int mt = 0; mt < 4; ++mt)
            #pragma unroll
            for (int nt = 0; nt < 2; ++nt)
                acc[mt][nt] = __builtin_amdgcn_mfma_f32_16x16x32_bf16(
                    af[mt], bf[nt], acc[mt][nt], 0, 0, 0);
        __syncthreads();
    }
    #pragma unroll
    for (int mt = 0; mt < 4; ++mt) {
        #pragma unroll
        for (int r = 0; r < 4; ++r) {
            int co = wv * 64 + mt * 16 + quad * 4 + r;
            float bco = bias1[co];
            size_t base = ((size_t)b * C_ + co) * HW_ + pix0;
            #pragma unroll
            for (int nt = 0; nt < 2; ++nt) {
                int col = nt * 16 + l15;
                out_f[base + col] = acc[mt][nt][r] + bco + auxf[base + col];
            }
        }
    }
}

// ---------------- launch ----------------------------------------------------
extern "C" void kernel_launch(void* const* d_in, const int* in_sizes, int n_in,
                              void* d_out, int out_size, void* d_ws, size_t ws_size,
                              hipStream_t stream) {
    const float* x     = (const float*)d_in[0];
    const float* p_w   = (const float*)d_in[1];
    const float* p_b   = (const float*)d_in[2];
    const float* ak_w  = (const float*)d_in[3];
    const float* ak_g  = (const float*)d_in[4];
    const float* ak_b  = (const float*)d_in[5];
    const float* l0_w  = (const float*)d_in[6];
    const float* l0_b  = (const float*)d_in[7];
    const float* ls_w  = (const float*)d_in[8];
    const float* ls_b  = (const float*)d_in[9];
    const float* l1_w  = (const float*)d_in[10];
    const float* l1_b  = (const float*)d_in[11];
    const float* cv_w  = (const float*)d_in[12];
    const float* cv_b  = (const float*)d_in[13];
    float* out = (float*)d_out;

    char* w = (char*)d_ws;
    unsigned short* wak = (unsigned short*)(w + 2359296);    // 384 KB
    unsigned short* wl1 = (unsigned short*)(w + 2752512);    // 128 KB
    unsigned short* wcv = (unsigned short*)(w + 2883584);    // 128 KB
    float* p1 = (float*)(w + 3014656);                       // 512 KB
    float* p2 = (float*)(w + 3538944);                       // 512 KB
    float* ss = (float*)(w + 4063232);                       // 2 KB
    float* pwt = (float*)(w + 4065280);                      // 72 KB
    // time-multiplexed regions:
    unsigned short* xt = (unsigned short*)(w + 4194304);     // 16 MB bf16 (dead after gather)
    unsigned short* ybh    = (unsigned short*)(w + 4194304); // 16 MB (ak writes, after gather)
    unsigned short* dw5out = (unsigned short*)(w + 20971520);// 16 MB
    float* part = (float*)(w + 37748736);                    // 6.3 MB (dead after gather)
    unsigned short* attn   = (unsigned short*)(w + 37748736);// 16 MB (dw7 out)
    unsigned short* v      = (unsigned short*)(w + 44040192);// 48 MB (dead after ak)

    prep_transpose_kernel<<<2376, 256, 0, stream>>>(ak_w, l1_w, cv_w, p_w,
                                                    wak, wl1, wcv, pwt, x, xt);
    offset_s1_kernel<<<4096, 256, 0, stream>>>(x, pwt, part);
    gather_kernel<<<1536, 256, 0, stream>>>(xt, part, p_b, v);
    ak_mfma_kernel<<<1024, 256, 0, stream>>>(v, wak, ybh, p1, p2);
    bn_stats_kernel<<<256, 256, 0, stream>>>(p1, p2, ak_g, ak_b, ss);
    dw5_fused_kernel<<<2048, 256, 0, stream>>>(ybh, ss, l0_w, l0_b, dw5out);
    dw7d3_kernel<<<2048, 256, 0, stream>>>(dw5out, ls_w, ls_b, attn);
    gemm_fused_kernel<<<1024, 256, 0, stream>>>(attn, wl1, l1_b, wcv, cv_b, ybh, ss, x, out);
}